// Round 8
// baseline (4673.161 us; speedup 1.0000x reference)
//
#include <hip/hip_runtime.h>
#include <hip/hip_bf16.h>

#define HID   512
#define SEQ   1024
#define GATES 2048       // 4*HID

// ---------------------------------------------------------------- helpers
__device__ __forceinline__ float sigm(float x) {
    return 1.f / (1.f + __expf(-x));
}
__device__ __forceinline__ float tanh_fast(float x) {
    float ax = fabsf(x);
    float e  = __expf(-2.f * ax);
    float t  = (1.f - e) * __builtin_amdgcn_rcpf(1.f + e);
    return copysignf(t, x);
}
__device__ __forceinline__ float bcast(float v, int l) {
    return __uint_as_float((unsigned)__builtin_amdgcn_readlane((int)__float_as_uint(v), l));
}

// ---------------------------------------------------------------- embedding (+ Hgate tag-clear)
__global__ void embed_kernel(const int* __restrict__ wi, const int* __restrict__ pi,
                             const float* __restrict__ we, const float* __restrict__ pe,
                             float* __restrict__ x, unsigned long long* __restrict__ Hgate) {
    // zero the gate-publication tags (32 MB) so stale tags can never alias
    size_t gtid = (size_t)blockIdx.x * 128 + threadIdx.x;
    for (size_t k = gtid; k < (size_t)SEQ * 2 * GATES; k += (size_t)1024 * 128)
        Hgate[k] = 0ull;
    int i = blockIdx.x;          // token 0..1023
    int t = threadIdx.x;         // 128 threads
    const float* w = we + (size_t)wi[i] * 300;
    const float* p = pe + (size_t)pi[i] * 100;
    float* xo = x + (size_t)i * 400;
    for (int c = t; c < 300; c += 128) xo[c]       = w[c];
    for (int c = t; c < 100; c += 128) xo[300 + c] = p[c];
}

// ---------------------------------------------------------------- fp32 GEMM pair, 128x64 tile (R1-proven):
// blockIdx.z selects {B,bias,C}; C[M,N] = A[M,K] @ B[N,K]^T + bias[N].
__global__ __launch_bounds__(256)
void gemm_bias2(const float* __restrict__ A,
                const float* __restrict__ B0, const float* __restrict__ bias0, float* __restrict__ C0,
                const float* __restrict__ B1, const float* __restrict__ bias1, float* __restrict__ C1,
                int M, int N, int K, int lda, int ldb, int ldc) {
    const float* B    = blockIdx.z ? B1    : B0;
    const float* bias = blockIdx.z ? bias1 : bias0;
    float*       C    = blockIdx.z ? C1    : C0;

    __shared__ __align__(16) float As[16 * 132];
    __shared__ __align__(16) float Bs[16 * 68];
    const int tid  = threadIdx.x;
    const int bn   = blockIdx.x, bm = blockIdx.y;
    const int tj   = tid & 15, ti = tid >> 4;
    const int arow = tid >> 1;               // 0..127
    const int ak8  = (tid & 1) * 8;          // 0 or 8
    const int brow = tid >> 2;               // 0..63
    const int bk4  = (tid & 3) * 4;          // 0,4,8,12
    float acc[8][4] = {};

    for (int kt = 0; kt < K; kt += 16) {
        float4 a0 = *(const float4*)(A + (size_t)(bm * 128 + arow) * lda + kt + ak8);
        float4 a1 = *(const float4*)(A + (size_t)(bm * 128 + arow) * lda + kt + ak8 + 4);
        float4 bv = *(const float4*)(B + (size_t)(bn * 64 + brow) * ldb + kt + bk4);
        As[(ak8 + 0) * 132 + arow] = a0.x; As[(ak8 + 1) * 132 + arow] = a0.y;
        As[(ak8 + 2) * 132 + arow] = a0.z; As[(ak8 + 3) * 132 + arow] = a0.w;
        As[(ak8 + 4) * 132 + arow] = a1.x; As[(ak8 + 5) * 132 + arow] = a1.y;
        As[(ak8 + 6) * 132 + arow] = a1.z; As[(ak8 + 7) * 132 + arow] = a1.w;
        Bs[(bk4 + 0) * 68 + brow] = bv.x; Bs[(bk4 + 1) * 68 + brow] = bv.y;
        Bs[(bk4 + 2) * 68 + brow] = bv.z; Bs[(bk4 + 3) * 68 + brow] = bv.w;
        __syncthreads();
        #pragma unroll
        for (int k = 0; k < 16; ++k) {
            float4 x0 = *(const float4*)&As[k * 132 + ti * 8];
            float4 x1 = *(const float4*)&As[k * 132 + ti * 8 + 4];
            float4 b4 = *(const float4*)&Bs[k * 68 + tj * 4];
            const float av[8] = {x0.x, x0.y, x0.z, x0.w, x1.x, x1.y, x1.z, x1.w};
            #pragma unroll
            for (int i = 0; i < 8; ++i) {
                acc[i][0] = fmaf(av[i], b4.x, acc[i][0]);
                acc[i][1] = fmaf(av[i], b4.y, acc[i][1]);
                acc[i][2] = fmaf(av[i], b4.z, acc[i][2]);
                acc[i][3] = fmaf(av[i], b4.w, acc[i][3]);
            }
        }
        __syncthreads();
    }
    const int n0 = bn * 64 + tj * 4;
    float bb0 = 0.f, bb1 = 0.f, bb2 = 0.f, bb3 = 0.f;
    if (bias) { bb0 = bias[n0]; bb1 = bias[n0 + 1]; bb2 = bias[n0 + 2]; bb3 = bias[n0 + 3]; }
    #pragma unroll
    for (int i = 0; i < 8; ++i) {
        float4 o;
        o.x = acc[i][0] + bb0; o.y = acc[i][1] + bb1;
        o.z = acc[i][2] + bb2; o.w = acc[i][3] + bb3;
        *(float4*)(C + (size_t)(bm * 128 + ti * 8 + i) * ldc + n0) = o;
    }
}

// ---------------------------------------------------------------- persistent bidirectional LSTM layer
// R14 = R8 structure (proven poll + per-step __syncthreads) with PUBLISH-EARLY:
// the producer publishes (tag | activated_gate) for all 64 gate rows right
// after the nonlinearity — one wave-store, before the shfl-gather/c-update/
// tanh/pack tail (which now runs off-path, only to produce Hout for the
// downstream GEMMs). Each consumer lane maintains a replicated cell state
// for its 64 h-units: c = fmaf(f,c,i*g); h = o*tanh_fast(c) — expressions
// are IDENTICAL to the producer's, so c is bit-identical on both sides.
// 64 WGs x 576 threads (9 waves). Wave 0 = producer; waves 1..8 = k-chunks.
__global__ __launch_bounds__(576)
void lstm_layer(const float* __restrict__ Zf, const float* __restrict__ Zr,
                const float* __restrict__ WhhF, const float* __restrict__ WhhR,
                unsigned long long* __restrict__ Hgate, // [SEQ][2][GATES] (tag|act_gate)
                float* __restrict__ Hout,               // [SEQ][2*HID] plain fp32
                unsigned tagBase) {
    const int dir = blockIdx.x >> 5;
    const int wg  = blockIdx.x & 31;
    const float* __restrict__ Z   = dir ? Zr   : Zf;
    const float* __restrict__ Whh = dir ? WhhR : WhhF;
    const int colOff = dir ? HID : 0;

    const int tid  = threadIdx.x;
    const int wave = tid >> 6;        // 0 = producer; 1..8 = k-chunks
    const int lane = tid & 63;        // local gate row 0..63
    const int g    = lane >> 4;       // gate 0..3 (i,f,g,o)
    const int jj   = lane & 15;       // local hidden unit 0..15
    const int grow = g * HID + wg * 16 + jj;   // row in Whh [2048 x 512]

    __shared__ float part[2][8 * 65];

    if (wave == 0) {
        // ---------------- producer wave ----------------
        float cval = 0.f;                 // cell state (lanes 0..15)
        float zin = Z[(size_t)(dir ? (SEQ - 1) : 0) * GATES + grow];
        for (int s = 0; s < SEQ; ++s) {
            const int t = dir ? (SEQ - 1 - s) : s;
            float znxt = 0.f;
            if (s + 1 < SEQ) {
                const int tn = dir ? (SEQ - 2 - s) : (s + 1);
                znxt = Z[(size_t)tn * GATES + grow];
            }
            __syncthreads();   // partials of step s are ready
            const float* pp = part[s & 1];
            float r = zin;
            #pragma unroll
            for (int c = 0; c < 8; ++c) r += pp[c * 65 + lane];
            float nl = (g == 2) ? tanh_fast(r) : sigm(r);
            // PUBLISH EARLY: one wave-store of all 64 activated gate rows
            unsigned long long pk = ((unsigned long long)(tagBase + (unsigned)s) << 32)
                                  | (unsigned long long)__float_as_uint(nl);
            __hip_atomic_store(Hgate + ((size_t)t * 2 + dir) * GATES + grow, pk,
                               __ATOMIC_RELAXED, __HIP_MEMORY_SCOPE_AGENT);
            // off-critical-path: finish h for the downstream GEMMs
            float ig = __shfl(nl, jj);
            float fg = __shfl(nl, 16 + jj);
            float gg = __shfl(nl, 32 + jj);
            float og = __shfl(nl, 48 + jj);
            if (lane < 16) {
                cval = fmaf(fg, cval, ig * gg);
                float hv = og * tanh_fast(cval);
                Hout[(size_t)t * (2 * HID) + colOff + wg * 16 + lane] = hv;
            }
            zin = znxt;
        }
    } else {
        // ---------------- matvec waves (k-chunks) ----------------
        const int kc = wave - 1;          // k-chunk 0..7 (h[64*kc .. +64))
        float w[64];
        {
            const float4* wp = (const float4*)(Whh + (size_t)grow * HID + kc * 64);
            #pragma unroll
            for (int q = 0; q < 16; ++q) {
                float4 v = wp[q];
                w[4 * q] = v.x; w[4 * q + 1] = v.y; w[4 * q + 2] = v.z; w[4 * q + 3] = v.w;
            }
        }
        float ccell = 0.f;                // replicated cell state for unit kc*64+lane
        for (int s = 0; s < SEQ; ++s) {
            const int t = dir ? (SEQ - 1 - s) : s;
            float acc = 0.f;
            if (s > 0) {
                const int tp = dir ? (t + 1) : (t - 1);
                const unsigned expTag = tagBase + (unsigned)s - 1u;
                const unsigned long long* gp =
                    Hgate + ((size_t)tp * 2 + dir) * GATES + kc * 64 + lane;
                // 2-slot quad poll (proven R8 structure, 4 gate addrs per slot)
                #define LDG(o) __hip_atomic_load(gp + (o), __ATOMIC_RELAXED, __HIP_MEMORY_SCOPE_AGENT)
                #define OKT(x) ((unsigned)((x) >> 32) == expTag)
                unsigned long long ia, fa, ga, oa, ib, fb, gb, ob, vi, vf, vg, vo;
                ia = LDG(0); fa = LDG(512); ga = LDG(1024); oa = LDG(1536);
                for (;;) {
                    ib = LDG(0); fb = LDG(512); gb = LDG(1024); ob = LDG(1536);
                    if (__all(OKT(ia) & OKT(fa) & OKT(ga) & OKT(oa))) {
                        vi = ia; vf = fa; vg = ga; vo = oa; break;
                    }
                    ia = LDG(0); fa = LDG(512); ga = LDG(1024); oa = LDG(1536);
                    if (__all(OKT(ib) & OKT(fb) & OKT(gb) & OKT(ob))) {
                        vi = ib; vf = fb; vg = gb; vo = ob; break;
                    }
                }
                #undef LDG
                #undef OKT
                float iv = __uint_as_float((unsigned)vi);
                float fv = __uint_as_float((unsigned)vf);
                float gv = __uint_as_float((unsigned)vg);
                float ov = __uint_as_float((unsigned)vo);
                // replicate the producer's exact update (bit-identical)
                ccell = fmaf(fv, ccell, iv * gv);
                float hv = ov * tanh_fast(ccell);   // h[64*kc + lane]
                float a0 = 0.f, a1 = 0.f, a2 = 0.f, a3 = 0.f;
                #pragma unroll
                for (int m = 0; m < 64; m += 4) {
                    a0 = fmaf(w[m + 0], bcast(hv, m + 0), a0);
                    a1 = fmaf(w[m + 1], bcast(hv, m + 1), a1);
                    a2 = fmaf(w[m + 2], bcast(hv, m + 2), a2);
                    a3 = fmaf(w[m + 3], bcast(hv, m + 3), a3);
                }
                acc = (a0 + a1) + (a2 + a3);
            }
            part[s & 1][kc * 65 + lane] = acc;
            __syncthreads();
        }
    }
}

// ---------------------------------------------------------------- pairwise MLP scores (R1-proven)
__global__ __launch_bounds__(256)
void pairwise_kernel(const float* __restrict__ Ah, const float* __restrict__ Bd,
                     const float* __restrict__ w2, const float* __restrict__ b2,
                     float* __restrict__ out) {
    __shared__ __align__(16) float at[16 * 260];
    __shared__ __align__(16) float bt[16 * 260];
    __shared__ __align__(16) float wl[256];
    const int tid = threadIdx.x;
    const int i0 = blockIdx.y * 16, j0 = blockIdx.x * 16;
    for (int u = tid; u < 16 * 256; u += 256) {
        int r = u >> 8, m = u & 255;
        at[r * 260 + m] = Ah[(size_t)(i0 + r) * 256 + m];
        bt[r * 260 + m] = Bd[(size_t)(j0 + r) * 256 + m];
    }
    wl[tid] = w2[tid];
    __syncthreads();
    const int tj = tid & 15, ti = tid >> 4;
    float acc = b2[0];
    #pragma unroll 2
    for (int m = 0; m < 256; m += 4) {
        float4 a4 = *(const float4*)&at[ti * 260 + m];
        float4 b4 = *(const float4*)&bt[tj * 260 + m];
        float4 w4 = *(const float4*)&wl[m];
        acc += tanh_fast(a4.x + b4.x) * w4.x;
        acc += tanh_fast(a4.y + b4.y) * w4.y;
        acc += tanh_fast(a4.z + b4.z) * w4.z;
        acc += tanh_fast(a4.w + b4.w) * w4.w;
    }
    out[(size_t)(i0 + ti) * 1024 + (j0 + tj)] = acc;
}

// ---------------------------------------------------------------- launch
extern "C" void kernel_launch(void* const* d_in, const int* in_sizes, int n_in,
                              void* d_out, int out_size, void* d_ws, size_t ws_size,
                              hipStream_t stream) {
    const int*   wi    = (const int*)  d_in[0];
    const int*   pi    = (const int*)  d_in[1];
    const float* we    = (const float*)d_in[2];
    const float* pe    = (const float*)d_in[3];
    const float* wih0f = (const float*)d_in[4];
    const float* whh0f = (const float*)d_in[5];
    const float* b0f   = (const float*)d_in[6];
    const float* wih0r = (const float*)d_in[7];
    const float* whh0r = (const float*)d_in[8];
    const float* b0r   = (const float*)d_in[9];
    const float* wih1f = (const float*)d_in[10];
    const float* whh1f = (const float*)d_in[11];
    const float* b1f   = (const float*)d_in[12];
    const float* wih1r = (const float*)d_in[13];
    const float* whh1r = (const float*)d_in[14];
    const float* b1r   = (const float*)d_in[15];
    const float* W1    = (const float*)d_in[16];
    const float* bmlp1 = (const float*)d_in[17];
    const float* w2    = (const float*)d_in[18];
    const float* b2    = (const float*)d_in[19];
    float* out = (float*)d_out;

    char* wsb = (char*)d_ws;
    float* x  = (float*)(wsb + 512);          // 1024*400
    float* zA = x  + (size_t)1024 * 400;      // 1024*2048
    float* zB = zA + (size_t)1024 * 2048;     // 1024*2048
    float* h0 = zB + (size_t)1024 * 2048;     // 1024*1024
    float* h1 = h0 + (size_t)1024 * 1024;     // 1024*1024
    float* aH = h1 + (size_t)1024 * 1024;     // 1024*256
    float* bD = aH + (size_t)1024 * 256;      // 1024*256
    unsigned long long* Hgate = (unsigned long long*)(bD + (size_t)1024 * 256); // [1024][2][2048] u64 = 32MB

    embed_kernel<<<dim3(1024), dim3(128), 0, stream>>>(wi, pi, we, pe, x, Hgate);

    // layer-0 input projections (both directions): [1024,400]@[2048,400]^T
    gemm_bias2<<<dim3(32, 8, 2), dim3(256), 0, stream>>>(
        x, wih0f, b0f, zA, wih0r, b0r, zB, 1024, 2048, 400, 400, 400, 2048);

    lstm_layer<<<dim3(64), dim3(576), 0, stream>>>(zA, zB, whh0f, whh0r, Hgate, h0, 1u);

    // layer-1 input projections (both directions): [1024,1024]@[2048,1024]^T
    gemm_bias2<<<dim3(32, 8, 2), dim3(256), 0, stream>>>(
        h0, wih1f, b1f, zA, wih1r, b1r, zB, 1024, 2048, 1024, 1024, 1024, 2048);

    lstm_layer<<<dim3(64), dim3(576), 0, stream>>>(zA, zB, whh1f, whh1r, Hgate, h1, 8192u);

    // head/dep projections (one launch): [1024,1024]@[256,1024]^T (bmlp1 folded into aH)
    gemm_bias2<<<dim3(4, 8, 2), dim3(256), 0, stream>>>(
        h1, W1, bmlp1, aH, W1 + 1024, nullptr, bD, 1024, 256, 1024, 1024, 2048, 256);

    pairwise_kernel<<<dim3(64, 64), dim3(256), 0, stream>>>(aH, bD, w2, b2, out);
}

// Round 9
// 3370.218 us; speedup vs baseline: 1.3866x; 1.3866x over previous
//
#include <hip/hip_runtime.h>
#include <hip/hip_bf16.h>

#define HID   512
#define SEQ   1024
#define GATES 2048       // 4*HID

// ---------------------------------------------------------------- helpers
__device__ __forceinline__ float sigm(float x) {
    return 1.f / (1.f + __expf(-x));
}
__device__ __forceinline__ float tanh_fast(float x) {
    float ax = fabsf(x);
    float e  = __expf(-2.f * ax);
    float t  = (1.f - e) * __builtin_amdgcn_rcpf(1.f + e);
    return copysignf(t, x);
}
__device__ __forceinline__ float bcast(float v, int l) {
    return __uint_as_float((unsigned)__builtin_amdgcn_readlane((int)__float_as_uint(v), l));
}

// ---------------------------------------------------------------- embedding
__global__ void embed_kernel(const int* __restrict__ wi, const int* __restrict__ pi,
                             const float* __restrict__ we, const float* __restrict__ pe,
                             float* __restrict__ x) {
    int i = blockIdx.x;          // token 0..1023
    int t = threadIdx.x;         // 128 threads
    const float* w = we + (size_t)wi[i] * 300;
    const float* p = pe + (size_t)pi[i] * 100;
    float* xo = x + (size_t)i * 400;
    for (int c = t; c < 300; c += 128) xo[c]       = w[c];
    for (int c = t; c < 100; c += 128) xo[300 + c] = p[c];
}

// ---------------------------------------------------------------- fp32 GEMM pair, 128x64 tile:
// blockIdx.z selects {B,bias,C}; C[M,N] = A[M,K] @ B[N,K]^T + bias[N].
// M mult of 128, N mult of 64, K mult of 16. 256 threads, 8x4 acc/thread.
// LDS TRANSPOSED [k][row] (A stride 132, B stride 68); inner: 3x ds_read_b128
// + 32 fma. Write conflicts <=2-way (free); A-read 4-way b128 (1.58x, ok).
__global__ __launch_bounds__(256)
void gemm_bias2(const float* __restrict__ A,
                const float* __restrict__ B0, const float* __restrict__ bias0, float* __restrict__ C0,
                const float* __restrict__ B1, const float* __restrict__ bias1, float* __restrict__ C1,
                int M, int N, int K, int lda, int ldb, int ldc) {
    const float* B    = blockIdx.z ? B1    : B0;
    const float* bias = blockIdx.z ? bias1 : bias0;
    float*       C    = blockIdx.z ? C1    : C0;

    __shared__ __align__(16) float As[16 * 132];
    __shared__ __align__(16) float Bs[16 * 68];
    const int tid  = threadIdx.x;
    const int bn   = blockIdx.x, bm = blockIdx.y;
    const int tj   = tid & 15, ti = tid >> 4;
    const int arow = tid >> 1;               // 0..127
    const int ak8  = (tid & 1) * 8;          // 0 or 8
    const int brow = tid >> 2;               // 0..63
    const int bk4  = (tid & 3) * 4;          // 0,4,8,12
    float acc[8][4] = {};

    for (int kt = 0; kt < K; kt += 16) {
        float4 a0 = *(const float4*)(A + (size_t)(bm * 128 + arow) * lda + kt + ak8);
        float4 a1 = *(const float4*)(A + (size_t)(bm * 128 + arow) * lda + kt + ak8 + 4);
        float4 bv = *(const float4*)(B + (size_t)(bn * 64 + brow) * ldb + kt + bk4);
        As[(ak8 + 0) * 132 + arow] = a0.x; As[(ak8 + 1) * 132 + arow] = a0.y;
        As[(ak8 + 2) * 132 + arow] = a0.z; As[(ak8 + 3) * 132 + arow] = a0.w;
        As[(ak8 + 4) * 132 + arow] = a1.x; As[(ak8 + 5) * 132 + arow] = a1.y;
        As[(ak8 + 6) * 132 + arow] = a1.z; As[(ak8 + 7) * 132 + arow] = a1.w;
        Bs[(bk4 + 0) * 68 + brow] = bv.x; Bs[(bk4 + 1) * 68 + brow] = bv.y;
        Bs[(bk4 + 2) * 68 + brow] = bv.z; Bs[(bk4 + 3) * 68 + brow] = bv.w;
        __syncthreads();
        #pragma unroll
        for (int k = 0; k < 16; ++k) {
            float4 x0 = *(const float4*)&As[k * 132 + ti * 8];
            float4 x1 = *(const float4*)&As[k * 132 + ti * 8 + 4];
            float4 b4 = *(const float4*)&Bs[k * 68 + tj * 4];
            const float av[8] = {x0.x, x0.y, x0.z, x0.w, x1.x, x1.y, x1.z, x1.w};
            #pragma unroll
            for (int i = 0; i < 8; ++i) {
                acc[i][0] = fmaf(av[i], b4.x, acc[i][0]);
                acc[i][1] = fmaf(av[i], b4.y, acc[i][1]);
                acc[i][2] = fmaf(av[i], b4.z, acc[i][2]);
                acc[i][3] = fmaf(av[i], b4.w, acc[i][3]);
            }
        }
        __syncthreads();
    }
    const int n0 = bn * 64 + tj * 4;
    float bb0 = 0.f, bb1 = 0.f, bb2 = 0.f, bb3 = 0.f;
    if (bias) { bb0 = bias[n0]; bb1 = bias[n0 + 1]; bb2 = bias[n0 + 2]; bb3 = bias[n0 + 3]; }
    #pragma unroll
    for (int i = 0; i < 8; ++i) {
        float4 o;
        o.x = acc[i][0] + bb0; o.y = acc[i][1] + bb1;
        o.z = acc[i][2] + bb2; o.w = acc[i][3] + bb3;
        *(float4*)(C + (size_t)(bm * 128 + ti * 8 + i) * ldc + n0) = o;
    }
}

// ---------------------------------------------------------------- persistent bidirectional LSTM layer
// R1-champion structure, byte-identical (1465 us/layer proven). Evidence that
// this is a fixed point of the communication scheme:
//  - per-step __syncthreads forces vmcnt(0) -> polls deeper than 2 slots pay
//    the drain back at the barrier (R6/R7 regressions);
//  - LDS release/acquire flags cost more than s_barrier (R7);
//  - sc0/L2 polls read stale lines cross-XCD (R2);
//  - concurrent bulk traffic inflates the L3 RTT (R3/R5);
//  - widening the handoff message multiplies poll traffic (R8).
// 64 WGs x 576 threads (9 waves). Wave 0 = producer/finisher; waves 1..8 =
// k-chunk matvec. WGs [0,32): forward; [32,64): reverse. Each WG owns 16
// hidden units = 64 gate rows. lane = gate row.
__global__ __launch_bounds__(576)
void lstm_layer(const float* __restrict__ Zf, const float* __restrict__ Zr,
                const float* __restrict__ WhhF, const float* __restrict__ WhhR,
                unsigned long long* __restrict__ Hpair, // [SEQ][2*HID] (tag|h)
                float* __restrict__ Hout,               // [SEQ][2*HID] plain fp32
                unsigned tagBase) {
    const int dir = blockIdx.x >> 5;
    const int wg  = blockIdx.x & 31;
    const float* __restrict__ Z   = dir ? Zr   : Zf;
    const float* __restrict__ Whh = dir ? WhhR : WhhF;
    const int colOff = dir ? HID : 0;

    const int tid  = threadIdx.x;
    const int wave = tid >> 6;        // 0 = producer; 1..8 = k-chunks
    const int lane = tid & 63;        // local gate row 0..63
    const int g    = lane >> 4;       // gate 0..3 (i,f,g,o)
    const int jj   = lane & 15;       // local hidden unit 0..15
    const int grow = g * HID + wg * 16 + jj;   // row in Whh [2048 x 512]

    __shared__ float part[2][8 * 65];

    if (wave == 0) {
        // ---------------- producer / finisher wave ----------------
        float cval = 0.f;                 // cell state (lanes 0..15)
        float zin = Z[(size_t)(dir ? (SEQ - 1) : 0) * GATES + grow];
        for (int s = 0; s < SEQ; ++s) {
            const int t = dir ? (SEQ - 1 - s) : s;
            float znxt = 0.f;
            if (s + 1 < SEQ) {
                const int tn = dir ? (SEQ - 2 - s) : (s + 1);
                znxt = Z[(size_t)tn * GATES + grow];
            }
            __syncthreads();   // partials of step s are ready
            const float* pp = part[s & 1];
            float r = zin;
            #pragma unroll
            for (int c = 0; c < 8; ++c) r += pp[c * 65 + lane];
            float nl = (g == 2) ? tanh_fast(r) : sigm(r);
            float ig = __shfl(nl, jj);
            float fg = __shfl(nl, 16 + jj);
            float gg = __shfl(nl, 32 + jj);
            float og = __shfl(nl, 48 + jj);
            if (lane < 16) {
                cval = fg * cval + ig * gg;
                float hv = og * tanh_fast(cval);
                const size_t oidx = (size_t)t * (2 * HID) + colOff + wg * 16 + lane;
                unsigned long long pk = ((unsigned long long)(tagBase + (unsigned)s) << 32)
                                      | (unsigned long long)__float_as_uint(hv);
                __hip_atomic_store(Hpair + oidx, pk, __ATOMIC_RELAXED, __HIP_MEMORY_SCOPE_AGENT);
                Hout[oidx] = hv;   // plain fp32 for downstream GEMMs (off critical path)
            }
            zin = znxt;
        }
    } else {
        // ---------------- matvec waves (k-chunks) ----------------
        const int kc = wave - 1;          // k-chunk 0..7 (h[64*kc .. +64))
        float w[64];
        {
            const float4* wp = (const float4*)(Whh + (size_t)grow * HID + kc * 64);
            #pragma unroll
            for (int q = 0; q < 16; ++q) {
                float4 v = wp[q];
                w[4 * q] = v.x; w[4 * q + 1] = v.y; w[4 * q + 2] = v.z; w[4 * q + 3] = v.w;
            }
        }
        for (int s = 0; s < SEQ; ++s) {
            const int t = dir ? (SEQ - 1 - s) : s;
            float acc = 0.f;
            if (s > 0) {
                const int tp = dir ? (t + 1) : (t - 1);
                const unsigned expTag = tagBase + (unsigned)s - 1u;
                const unsigned long long* hp =
                    Hpair + (size_t)tp * (2 * HID) + colOff + kc * 64 + lane;
                // pipelined poll: keep 2 loads in flight, check every ~latency/2
                unsigned long long va, vb, v;
                va = __hip_atomic_load(hp, __ATOMIC_RELAXED, __HIP_MEMORY_SCOPE_AGENT);
                for (;;) {
                    vb = __hip_atomic_load(hp, __ATOMIC_RELAXED, __HIP_MEMORY_SCOPE_AGENT);
                    if (__all((unsigned)(va >> 32) == expTag)) { v = va; break; }
                    va = __hip_atomic_load(hp, __ATOMIC_RELAXED, __HIP_MEMORY_SCOPE_AGENT);
                    if (__all((unsigned)(vb >> 32) == expTag)) { v = vb; break; }
                }
                float hv = __uint_as_float((unsigned)v);   // h[64*kc + lane]
                float a0 = 0.f, a1 = 0.f, a2 = 0.f, a3 = 0.f;
                #pragma unroll
                for (int m = 0; m < 64; m += 4) {
                    a0 = fmaf(w[m + 0], bcast(hv, m + 0), a0);
                    a1 = fmaf(w[m + 1], bcast(hv, m + 1), a1);
                    a2 = fmaf(w[m + 2], bcast(hv, m + 2), a2);
                    a3 = fmaf(w[m + 3], bcast(hv, m + 3), a3);
                }
                acc = (a0 + a1) + (a2 + a3);
            }
            part[s & 1][kc * 65 + lane] = acc;
            __syncthreads();
        }
    }
}

// ---------------------------------------------------------------- pairwise MLP scores
// R1 structure with ONE change: w2 is read straight from global via a
// wave-uniform address (scalar-load path / L1-resident) instead of being
// staged in LDS — removes 1/3 of the LDS issue in the dominant loop.
__global__ __launch_bounds__(256)
void pairwise_kernel(const float* __restrict__ Ah, const float* __restrict__ Bd,
                     const float* __restrict__ w2, const float* __restrict__ b2,
                     float* __restrict__ out) {
    __shared__ __align__(16) float at[16 * 260];
    __shared__ __align__(16) float bt[16 * 260];
    const int tid = threadIdx.x;
    const int i0 = blockIdx.y * 16, j0 = blockIdx.x * 16;
    for (int u = tid; u < 16 * 256; u += 256) {
        int r = u >> 8, m = u & 255;
        at[r * 260 + m] = Ah[(size_t)(i0 + r) * 256 + m];
        bt[r * 260 + m] = Bd[(size_t)(j0 + r) * 256 + m];
    }
    __syncthreads();
    const int tj = tid & 15, ti = tid >> 4;
    float acc = b2[0];
    #pragma unroll 2
    for (int m = 0; m < 256; m += 4) {
        float4 a4 = *(const float4*)&at[ti * 260 + m];
        float4 b4 = *(const float4*)&bt[tj * 260 + m];
        float4 w4 = *(const float4*)&w2[m];   // uniform addr -> scalar load
        acc += tanh_fast(a4.x + b4.x) * w4.x;
        acc += tanh_fast(a4.y + b4.y) * w4.y;
        acc += tanh_fast(a4.z + b4.z) * w4.z;
        acc += tanh_fast(a4.w + b4.w) * w4.w;
    }
    out[(size_t)(i0 + ti) * 1024 + (j0 + tj)] = acc;
}

// ---------------------------------------------------------------- launch
extern "C" void kernel_launch(void* const* d_in, const int* in_sizes, int n_in,
                              void* d_out, int out_size, void* d_ws, size_t ws_size,
                              hipStream_t stream) {
    const int*   wi    = (const int*)  d_in[0];
    const int*   pi    = (const int*)  d_in[1];
    const float* we    = (const float*)d_in[2];
    const float* pe    = (const float*)d_in[3];
    const float* wih0f = (const float*)d_in[4];
    const float* whh0f = (const float*)d_in[5];
    const float* b0f   = (const float*)d_in[6];
    const float* wih0r = (const float*)d_in[7];
    const float* whh0r = (const float*)d_in[8];
    const float* b0r   = (const float*)d_in[9];
    const float* wih1f = (const float*)d_in[10];
    const float* whh1f = (const float*)d_in[11];
    const float* b1f   = (const float*)d_in[12];
    const float* wih1r = (const float*)d_in[13];
    const float* whh1r = (const float*)d_in[14];
    const float* b1r   = (const float*)d_in[15];
    const float* W1    = (const float*)d_in[16];
    const float* bmlp1 = (const float*)d_in[17];
    const float* w2    = (const float*)d_in[18];
    const float* b2    = (const float*)d_in[19];
    float* out = (float*)d_out;

    char* wsb = (char*)d_ws;
    float* x  = (float*)(wsb + 512);          // 1024*400
    float* zA = x  + (size_t)1024 * 400;      // 1024*2048
    float* zB = zA + (size_t)1024 * 2048;     // 1024*2048
    float* h0 = zB + (size_t)1024 * 2048;     // 1024*1024
    float* h1 = h0 + (size_t)1024 * 1024;     // 1024*1024
    float* aH = h1 + (size_t)1024 * 1024;     // 1024*256
    float* bD = aH + (size_t)1024 * 256;      // 1024*256
    unsigned long long* Hpair = (unsigned long long*)(bD + (size_t)1024 * 256); // 1024*1024 u64

    embed_kernel<<<dim3(1024), dim3(128), 0, stream>>>(wi, pi, we, pe, x);

    // layer-0 input projections (both directions): [1024,400]@[2048,400]^T
    gemm_bias2<<<dim3(32, 8, 2), dim3(256), 0, stream>>>(
        x, wih0f, b0f, zA, wih0r, b0r, zB, 1024, 2048, 400, 400, 400, 2048);

    lstm_layer<<<dim3(64), dim3(576), 0, stream>>>(zA, zB, whh0f, whh0r, Hpair, h0, 1u);

    // layer-1 input projections (both directions): [1024,1024]@[2048,1024]^T
    gemm_bias2<<<dim3(32, 8, 2), dim3(256), 0, stream>>>(
        h0, wih1f, b1f, zA, wih1r, b1r, zB, 1024, 2048, 1024, 1024, 1024, 2048);

    lstm_layer<<<dim3(64), dim3(576), 0, stream>>>(zA, zB, whh1f, whh1r, Hpair, h1, 8192u);

    // head/dep projections (one launch): [1024,1024]@[256,1024]^T (bmlp1 folded into aH)
    gemm_bias2<<<dim3(4, 8, 2), dim3(256), 0, stream>>>(
        h1, W1, bmlp1, aH, W1 + 1024, nullptr, bD, 1024, 256, 1024, 1024, 2048, 256);

    pairwise_kernel<<<dim3(64, 64), dim3(256), 0, stream>>>(aH, bD, w2, b2, out);
}